// Round 1
// baseline (169.189 us; speedup 1.0000x reference)
//
#include <hip/hip_runtime.h>

// Enframe: out[bc, k, t] = x[bc, t*HOP + k], k in [0, FL), t in [0, T)
// B*C = 16, S = 480000, FL = 2048, HOP = 512, T = (S-FL)/HOP+1 = 934.
//
// Layout strategy:
//  - lanes along t  -> coalesced 256B/wave stores (write traffic dominates: 122MB)
//  - each thread owns a 64B line-aligned k-chunk (16 floats) at its t
//    -> every HBM read line fully consumed by one thread (4x dwordx4, L1-hit after 1st)
//  - grid.x = bc so linear block id % 8 == bc % 8 -> each XCD holds 2 input slabs
//    (3.84 MB <= 4 MB L2) for the 4x k/t read reuse
//  - nontemporal stores keep the 122MB write stream from evicting input in L2

constexpr int FL  = 2048;
constexpr int HOP = 512;

__global__ __launch_bounds__(256)
void enframe_kernel(const float* __restrict__ x, float* __restrict__ out,
                    int S, int T) {
    const int bc = blockIdx.x;              // 0..15, pins slab to XCD
    const int g  = blockIdx.y & 127;        // k-group of 16 floats (128 groups cover FL)
    const int tt = blockIdx.y >> 7;         // t-tile of 256
    const int t  = tt * 256 + threadIdx.x;
    if (t >= T) return;

    // 64B-aligned contiguous 16-float read, fully consumed by this thread
    const float4* xp = (const float4*)(x + (size_t)bc * S + (size_t)t * HOP + (size_t)g * 16);
    float4 v0 = xp[0];
    float4 v1 = xp[1];
    float4 v2 = xp[2];
    float4 v3 = xp[3];

    float* op = out + ((size_t)bc * FL + (size_t)g * 16) * T + t;
    float vals[16] = {v0.x, v0.y, v0.z, v0.w,
                      v1.x, v1.y, v1.z, v1.w,
                      v2.x, v2.y, v2.z, v2.w,
                      v3.x, v3.y, v3.z, v3.w};
#pragma unroll
    for (int j = 0; j < 16; ++j)
        __builtin_nontemporal_store(vals[j], op + (size_t)j * T);
}

extern "C" void kernel_launch(void* const* d_in, const int* in_sizes, int n_in,
                              void* d_out, int out_size, void* d_ws, size_t ws_size,
                              hipStream_t stream) {
    const float* x = (const float*)d_in[0];
    float* out = (float*)d_out;
    const int BC = 16;                 // B*C = 8*2
    const int S  = in_sizes[0] / BC;   // 480000
    const int T  = (S - FL) / HOP + 1; // 934
    const int t_tiles = (T + 255) / 256;
    dim3 grid(BC, (unsigned)(t_tiles * 128));
    enframe_kernel<<<grid, 256, 0, stream>>>(x, out, S, T);
}